// Round 14
// baseline (286.358 us; speedup 1.0000x reference)
//
#include <hip/hip_runtime.h>
#include <hip/hip_bf16.h>

#define L_Q 49
#define D_MODEL 256
#define NHEAD 8
#define DK 32
#define PP 41
#define POS_OFF 20

typedef __attribute__((ext_vector_type(8))) __bf16 bf16x8;
typedef __attribute__((ext_vector_type(4))) float f32x4;
typedef __attribute__((ext_vector_type(8))) unsigned short u16x8;

__device__ __forceinline__ float bf2f(unsigned short u) {
    return __uint_as_float(((unsigned)u) << 16);
}
__device__ __forceinline__ unsigned short f2bf(float f) {
    unsigned u = __float_as_uint(f);
    return (unsigned short)((u + 0x7FFF + ((u >> 16) & 1)) >> 16);
}

// ---------------- one-time W conversion to bf16, ROW-MAJOR (q-rows pre-scaled)
__global__ __launch_bounds__(256)
void convert_w(const float* __restrict__ W, const float* __restrict__ out_w,
               float scaling,
               unsigned short* __restrict__ wbf, unsigned short* __restrict__ owbf) {
    int i = blockIdx.x * 256 + threadIdx.x;   // 65536 float4 total
    if (i < 49152) {
        int row = i >> 6;
        float sc = (row < 256) ? scaling : 1.0f;
        float4 v = reinterpret_cast<const float4*>(W)[i];
        ushort4 o = { f2bf(v.x * sc), f2bf(v.y * sc), f2bf(v.z * sc), f2bf(v.w * sc) };
        reinterpret_cast<ushort4*>(wbf)[i] = o;
    } else {
        float4 v = reinterpret_cast<const float4*>(out_w)[i - 49152];
        ushort4 o = { f2bf(v.x), f2bf(v.y), f2bf(v.z), f2bf(v.w) };
        reinterpret_cast<ushort4*>(owbf)[i - 49152] = o;
    }
}

// ---------------- k_pos prep (f32 accumulate, bf16 store): kpb[which][p][d]
__global__ __launch_bounds__(256)
void prep_kpos(const float* __restrict__ pos_y, const float* __restrict__ pos_x,
               const float* __restrict__ W, unsigned short* __restrict__ kpb) {
    int p = blockIdx.x;
    int which = blockIdx.y;
    __shared__ float pr[128];
    int d = threadIdx.x;
    if (d < 128) pr[d] = which ? pos_x[p * 128 + d] : pos_y[p * 128 + d];
    __syncthreads();
    const float* Wk = W + 256 * 256;
    int fOff = which ? 128 : 0;
    float acc = 0.f;
    #pragma unroll 8
    for (int f = 0; f < 128; ++f)
        acc += pr[f] * Wk[(size_t)d * 256 + fOff + f];
    kpb[((size_t)which * PP + p) * 256 + d] = f2bf(acc);
}

// ---------------- m97-style proj + T4 COUNTED VMCNT (never drain to 0 in loop).
// r13 A/B: only the sync discipline changes. Per k-step:
//   s_waitcnt vmcnt(4)  [my stage-kk done; stage-kk+1 stays in flight]
//   s_barrier           [all waves' stage-kk landed]
//   ds_read frags -> regs; lgkmcnt(0); sched_barrier(0)   (rule #18)
//   s_barrier           [all waves done reading buf kk]
//   stage(kk+2) -> buf kk; 16 MFMAs
// Loads get a full extra k-step of flight; no vmcnt(0) drain in the loop (m218).
__global__ __launch_bounds__(512)
void proj_mfma(const float* __restrict__ Xq, const float* __restrict__ Xk,
               const float* __restrict__ Xv,
               const unsigned short* __restrict__ Wb,   // row-major 768x256 bf16
               const float* __restrict__ bias, float scaling,
               unsigned short* __restrict__ outq, unsigned short* __restrict__ outk,
               unsigned short* __restrict__ outv) {
    __shared__ unsigned char Sz[65536];     // [0,32K): A dbuf; [32K,64K): B dbuf
    __shared__ float Lb[256];
    int which = blockIdx.y;
    const float* X = (which == 0) ? Xq : ((which == 1) ? Xk : Xv);
    unsigned short* out = (which == 0) ? outq : ((which == 1) ? outk : outv);
    const char* wsrc = (const char*)(Wb + (size_t)which * 65536);

    int tid = threadIdx.x, wid = tid >> 6, lane = tid & 63;
    int rgrp = lane & 15, kgrp = lane >> 4;
    int wm = wid & 1, wn = wid >> 1;        // 2 m-tiles x 4 n-tiles of 64
    size_t tile0 = (size_t)blockIdx.x * 128;
    const char* xsrc = (const char*)X;

    // per-k-step staging: 2 A-insts + 2 B-insts per thread (4 vmcnt events)
    auto stage = [&](int kk, int buf) {
        #pragma unroll
        for (int it = 0; it < 2; ++it) {
            int c = wid + it * 8;                      // KB-chunk 0..15
            {   // A: arow = c*8 + (lane>>3); off = (lane&7)*16
                int arow = c * 8 + (lane >> 3);
                unsigned off = (unsigned)(lane & 7) * 16;
                unsigned gs = (unsigned)(kk * 128) + (off ^ (((unsigned)arow & 7) << 4));
                __builtin_amdgcn_global_load_lds(
                    xsrc + (tile0 + arow) * 1024 + gs,
                    (char*)Sz + buf * 16384 + c * 1024 + lane * 16, 16, 0, 0);
            }
            {   // B: ncol = c*16 + (lane>>2); off = (lane&3)*16
                int ncol = c * 16 + (lane >> 2);
                unsigned off = (unsigned)(lane & 3) * 16;
                unsigned gs = (unsigned)ncol * 512 + (unsigned)(kk * 64)
                            + (off ^ (((unsigned)ncol & 3) << 4));
                __builtin_amdgcn_global_load_lds(
                    wsrc + gs,
                    (char*)Sz + 32768 + buf * 16384 + c * 1024 + lane * 16, 16, 0, 0);
            }
        }
    };

    // bias first: its vmcnt drains here, BEFORE the stage queue is primed
    if (tid < 256) Lb[tid] = bias[which * 256 + tid] * ((which == 0) ? scaling : 1.0f);
    stage(0, 0);
    stage(1, 1);                                // 8 loads in flight per thread

    f32x4 acc[4][4];
    #pragma unroll
    for (int m = 0; m < 4; ++m)
        #pragma unroll
        for (int n = 0; n < 4; ++n) acc[m][n] = (f32x4){0.f, 0.f, 0.f, 0.f};

    #pragma unroll
    for (int kk = 0; kk < 8; ++kk) {
        int buf = kk & 1;
        if (kk < 7) asm volatile("s_waitcnt vmcnt(4)" ::: "memory");
        else        asm volatile("s_waitcnt vmcnt(0)" ::: "memory");
        __builtin_amdgcn_s_barrier();           // all waves' stage-kk landed

        const char* Az = (const char*)Sz + buf * 16384;
        const char* Bz = (const char*)Sz + 32768 + buf * 16384;

        bf16x8 bf[4], af[4];
        #pragma unroll
        for (int nt = 0; nt < 4; ++nt) {
            int ncol = wn * 64 + nt * 16 + rgrp;
            unsigned ad = (unsigned)ncol * 64
                        + (((unsigned)kgrp * 16) ^ (((unsigned)ncol & 3) << 4));
            bf[nt] = *reinterpret_cast<const bf16x8*>(Bz + ad);
        }
        #pragma unroll
        for (int mf = 0; mf < 4; ++mf) {
            int arow = wm * 64 + mf * 16 + rgrp;
            unsigned s = ((unsigned)arow & 7) << 4;
            f32x4 q0 = *reinterpret_cast<const f32x4*>(Az + (unsigned)arow * 128 + (((unsigned)kgrp * 32) ^ s));
            f32x4 q1 = *reinterpret_cast<const f32x4*>(Az + (unsigned)arow * 128 + (((unsigned)kgrp * 32 + 16) ^ s));
            af[mf][0] = (__bf16)q0[0]; af[mf][1] = (__bf16)q0[1];
            af[mf][2] = (__bf16)q0[2]; af[mf][3] = (__bf16)q0[3];
            af[mf][4] = (__bf16)q1[0]; af[mf][5] = (__bf16)q1[1];
            af[mf][6] = (__bf16)q1[2]; af[mf][7] = (__bf16)q1[3];
        }
        asm volatile("s_waitcnt lgkmcnt(0)" ::: "memory");
        __builtin_amdgcn_sched_barrier(0);      // rule #18: pin MFMA below the wait
        __builtin_amdgcn_s_barrier();           // all waves done reading buf kk
        if (kk < 6) stage(kk + 2, buf);         // refill the just-freed buffer

        #pragma unroll
        for (int mf = 0; mf < 4; ++mf)
            #pragma unroll
            for (int nt = 0; nt < 4; ++nt)
                acc[mf][nt] = __builtin_amdgcn_mfma_f32_16x16x32_bf16(bf[nt], af[mf], acc[mf][nt], 0, 0, 0);
    }

    // epilogue: lane's X-row = tile0 + wm*64 + mf*16 + rgrp; n = wn*64 + nt*16 + kgrp*4+i
    #pragma unroll
    for (int mf = 0; mf < 4; ++mf) {
        size_t xrow = tile0 + wm * 64 + mf * 16 + rgrp;
        #pragma unroll
        for (int nt = 0; nt < 4; ++nt) {
            int col = wn * 64 + nt * 16 + kgrp * 4;
            float4 bv = *reinterpret_cast<const float4*>(&Lb[col]);
            ushort4 pk;
            pk.x = f2bf(acc[mf][nt][0] + bv.x);
            pk.y = f2bf(acc[mf][nt][1] + bv.y);
            pk.z = f2bf(acc[mf][nt][2] + bv.z);
            pk.w = f2bf(acc[mf][nt][3] + bv.w);
            *reinterpret_cast<ushort4*>(&out[xrow * 256 + col]) = pk;
        }
    }
}

// ---------------- out projection, m97 structure (unchanged from r13)
__global__ __launch_bounds__(512)
void out_mfma(const unsigned short* __restrict__ Xb, const unsigned short* __restrict__ Wb,
              const float* __restrict__ bias, float* __restrict__ out) {
    __shared__ unsigned char Sz[49152];     // [0,16K): A dbuf(8K); [16K,48K): B dbuf(16K)
    __shared__ float Lb[256];
    int tid = threadIdx.x, wid = tid >> 6, lane = tid & 63;
    int rgrp = lane & 15, kgrp = lane >> 4;
    int wm = wid & 1, wn = wid >> 1;
    size_t tile0 = (size_t)blockIdx.x * 128;
    const char* xsrc = (const char*)Xb;
    const char* wsrc = (const char*)Wb;

    auto stage = [&](int kk, int buf) {
        {
            int arow = wid * 16 + (lane >> 2);
            unsigned off = (unsigned)(lane & 3) * 16;
            unsigned gs = (unsigned)(kk * 64) + (off ^ (((unsigned)arow & 3) << 4));
            __builtin_amdgcn_global_load_lds(
                xsrc + (tile0 + arow) * 512 + gs,
                (char*)Sz + buf * 8192 + wid * 1024 + lane * 16, 16, 0, 0);
        }
        #pragma unroll
        for (int it = 0; it < 2; ++it) {
            int c = wid + it * 8;
            int ncol = c * 16 + (lane >> 2);
            unsigned off = (unsigned)(lane & 3) * 16;
            unsigned gs = (unsigned)ncol * 512 + (unsigned)(kk * 64)
                        + (off ^ (((unsigned)ncol & 3) << 4));
            __builtin_amdgcn_global_load_lds(
                wsrc + gs,
                (char*)Sz + 16384 + buf * 16384 + c * 1024 + lane * 16, 16, 0, 0);
        }
    };

    stage(0, 0);
    if (tid < 256) Lb[tid] = bias[tid];
    __syncthreads();

    f32x4 acc[4][4];
    #pragma unroll
    for (int m = 0; m < 4; ++m)
        #pragma unroll
        for (int n = 0; n < 4; ++n) acc[m][n] = (f32x4){0.f, 0.f, 0.f, 0.f};

    int buf = 0;
    for (int kk = 0; kk < 8; ++kk) {
        if (kk < 7) stage(kk + 1, buf ^ 1);

        const char* Az = (const char*)Sz + buf * 8192;
        const char* Bz = (const char*)Sz + 16384 + buf * 16384;

        bf16x8 bf[4];
        #pragma unroll
        for (int nt = 0; nt < 4; ++nt) {
            int ncol = wn * 64 + nt * 16 + rgrp;
            unsigned ad = (unsigned)ncol * 64
                        + (((unsigned)kgrp * 16) ^ (((unsigned)ncol & 3) << 4));
            bf[nt] = *reinterpret_cast<const bf16x8*>(Bz + ad);
        }
        #pragma unroll
        for (int mf = 0; mf < 4; ++mf) {
            int arow = wm * 64 + mf * 16 + rgrp;
            unsigned ad = (unsigned)arow * 64
                        + (((unsigned)kgrp * 16) ^ (((unsigned)arow & 3) << 4));
            bf16x8 af = *reinterpret_cast<const bf16x8*>(Az + ad);
            #pragma unroll
            for (int nt = 0; nt < 4; ++nt)
                acc[mf][nt] = __builtin_amdgcn_mfma_f32_16x16x32_bf16(bf[nt], af, acc[mf][nt], 0, 0, 0);
        }
        __syncthreads();
        buf ^= 1;
    }

    #pragma unroll
    for (int mf = 0; mf < 4; ++mf) {
        size_t xrow = tile0 + wm * 64 + mf * 16 + rgrp;
        #pragma unroll
        for (int nt = 0; nt < 4; ++nt) {
            int col = wn * 64 + nt * 16 + kgrp * 4;
            float4 bv = *reinterpret_cast<const float4*>(&Lb[col]);
            float4 o;
            o.x = acc[mf][nt][0] + bv.x;
            o.y = acc[mf][nt][1] + bv.y;
            o.z = acc[mf][nt][2] + bv.z;
            o.w = acc[mf][nt][3] + bv.w;
            *reinterpret_cast<float4*>(&out[xrow * 256 + col]) = o;
        }
    }
}

// ---------------- MFMA fused attention: one (b,h) per 4-wave block (unchanged)
__global__ __launch_bounds__(256)
void attn_mfma(const unsigned short* __restrict__ qbuf,
               const unsigned short* __restrict__ kbuf,
               const unsigned short* __restrict__ vbuf,
               const unsigned short* __restrict__ kpb,
               const unsigned char* __restrict__ mask,
               unsigned short* __restrict__ ctx,
               int B) {
    __shared__ unsigned short Kp[96][40];
    __shared__ unsigned short Pt[64][72];
    __shared__ unsigned short Vt[32][72];
    __shared__ unsigned short postab[49][40];
    __shared__ int yy[L_Q], xx[L_Q];
    __shared__ unsigned char mb[52];

    int b = blockIdx.x, h = blockIdx.y;
    int tid = threadIdx.x, wid = tid >> 6, lane = tid & 63;
    int rgrp = lane & 15, kgrp = lane >> 4;
    size_t lstride = (size_t)B * D_MODEL;
    size_t base = (size_t)b * D_MODEL + (size_t)h * DK;

    if (tid < L_Q) mb[tid] = mask[(size_t)b * L_Q + tid];
    if (tid < 196) {
        int l = tid >> 2, c = tid & 3;
        u16x8 vv = *reinterpret_cast<const u16x8*>(vbuf + (size_t)l * lstride + base + c * 8);
        #pragma unroll
        for (int j = 0; j < 8; ++j) Vt[c * 8 + j][l] = vv[j];
    }
    for (int e = tid; e < 512; e += 256) {
        int d = e >> 4, s2 = 48 + (e & 15);
        if (s2 > 48) Vt[d][s2] = 0;
    }
    for (int t = tid; t < 384; t += 256) {
        int r = t >> 2, kc = t & 3;
        const unsigned short* src;
        if (r < 64) {
            int kr = min(r, 48);
            src = kbuf + (size_t)kr * lstride + base + kc * 8;
        } else if (r < 80) {
            int p = r - 64 + 13;
            src = kpb + (size_t)p * D_MODEL + h * DK + kc * 8;
        } else {
            int p = r - 80 + 13;
            src = kpb + (size_t)(PP + p) * D_MODEL + h * DK + kc * 8;
        }
        *reinterpret_cast<u16x8*>(&Kp[r][kc * 8]) = *reinterpret_cast<const u16x8*>(src);
    }
    __syncthreads();
    if (tid < L_Q) {
        int r = tid / 7, c = tid % 7;
        int sy = 0, sx = 0;
        for (int rr = 0; rr <= r; ++rr) sy += (mb[rr * 7 + c] == 0);
        for (int cc = 0; cc <= c; ++cc) sx += (mb[r * 7 + cc] == 0);
        yy[tid] = sy; xx[tid] = sx;
    }
    __syncthreads();

    int qrow = min(16 * wid + rgrp, 48);
    bf16x8 qfrag = *reinterpret_cast<const bf16x8*>(qbuf + (size_t)qrow * lstride + base + kgrp * 8);
    f32x4 acc[6];
    #pragma unroll
    for (int t = 0; t < 6; ++t) {
        bf16x8 bfrag = *reinterpret_cast<const bf16x8*>(&Kp[t * 16 + rgrp][kgrp * 8]);
        acc[t] = __builtin_amdgcn_mfma_f32_16x16x32_bf16(qfrag, bfrag,
                    (f32x4){0.f, 0.f, 0.f, 0.f}, 0, 0, 0);
    }

    #pragma unroll
    for (int i = 0; i < 4; ++i) {
        int l = 16 * wid + kgrp * 4 + i;
        if (l <= 48) {
            postab[l][rgrp]      = f2bf(acc[4][i]);
            postab[l][20 + rgrp] = f2bf(acc[5][i]);
        }
    }
    asm volatile("s_waitcnt lgkmcnt(0)" ::: "memory");

    #pragma unroll
    for (int i = 0; i < 4; ++i) {
        int l = 16 * wid + kgrp * 4 + i;
        int lc = min(l, 48);
        int yyl = yy[lc], xxl = xx[lc];
        float v[4];
        #pragma unroll
        for (int ct = 0; ct < 4; ++ct) {
            int s = ct * 16 + rgrp;
            int sc = min(s, 48);
            int iy = yyl - yy[sc] + (POS_OFF - 13);
            int ix = xxl - xx[sc] + (POS_OFF - 13);
            float val = acc[ct][i] + bf2f(postab[lc][iy]) + bf2f(postab[lc][20 + ix]);
            v[ct] = (s >= L_Q || mb[sc]) ? -1e30f : val;
        }
        float m = fmaxf(fmaxf(v[0], v[1]), fmaxf(v[2], v[3]));
        m = fmaxf(m, __shfl_xor(m, 1));
        m = fmaxf(m, __shfl_xor(m, 2));
        m = fmaxf(m, __shfl_xor(m, 4));
        m = fmaxf(m, __shfl_xor(m, 8));
        float ssum = 0.f, ex[4];
        #pragma unroll
        for (int ct = 0; ct < 4; ++ct) { ex[ct] = __expf(v[ct] - m); ssum += ex[ct]; }
        ssum += __shfl_xor(ssum, 1);
        ssum += __shfl_xor(ssum, 2);
        ssum += __shfl_xor(ssum, 4);
        ssum += __shfl_xor(ssum, 8);
        float is = 1.f / ssum;
        #pragma unroll
        for (int ct = 0; ct < 4; ++ct)
            Pt[l & 63][ct * 16 + rgrp] = f2bf(ex[ct] * is);
    }
    asm volatile("s_waitcnt lgkmcnt(0)" ::: "memory");

    f32x4 oacc[2];
    oacc[0] = (f32x4){0.f, 0.f, 0.f, 0.f};
    oacc[1] = (f32x4){0.f, 0.f, 0.f, 0.f};
    #pragma unroll
    for (int kc = 0; kc < 2; ++kc) {
        bf16x8 pa = *reinterpret_cast<const bf16x8*>(&Pt[16 * wid + rgrp][kc * 32 + kgrp * 8]);
        #pragma unroll
        for (int dt = 0; dt < 2; ++dt) {
            bf16x8 vb = *reinterpret_cast<const bf16x8*>(&Vt[dt * 16 + rgrp][kc * 32 + kgrp * 8]);
            oacc[dt] = __builtin_amdgcn_mfma_f32_16x16x32_bf16(pa, vb, oacc[dt], 0, 0, 0);
        }
    }
    #pragma unroll
    for (int dt = 0; dt < 2; ++dt)
        #pragma unroll
        for (int i = 0; i < 4; ++i) {
            int l = 16 * wid + kgrp * 4 + i;
            if (l <= 48)
                ctx[(size_t)l * lstride + base + dt * 16 + rgrp] = f2bf(oacc[dt][i]);
        }
}

extern "C" void kernel_launch(void* const* d_in, const int* in_sizes, int n_in,
                              void* d_out, int out_size, void* d_ws, size_t ws_size,
                              hipStream_t stream) {
    const float* query = (const float*)d_in[0];
    const float* key   = (const float*)d_in[1];
    const float* value = (const float*)d_in[2];
    const unsigned char* maskp = (const unsigned char*)d_in[3];
    const float* W     = (const float*)d_in[4];
    const float* bias  = (const float*)d_in[5];
    const float* out_w = (const float*)d_in[6];
    const float* out_b = (const float*)d_in[7];
    const float* pos_x = (const float*)d_in[8];
    const float* pos_y = (const float*)d_in[9];
    float* out = (float*)d_out;

    int B = in_sizes[0] / (L_Q * D_MODEL);        // 2048
    int M = L_Q * B;                              // 100352 = 784 * 128

    size_t nqkv = (size_t)M * D_MODEL;
    unsigned short* qb = (unsigned short*)d_ws;
    unsigned short* kb = qb + nqkv;
    unsigned short* vb = kb + nqkv;
    unsigned short* kpb = vb + nqkv;
    unsigned short* wbf = kpb + 2 * PP * D_MODEL; // row-major 768x256 bf16
    unsigned short* owbf = wbf + 768 * 256;       // row-major 256x256 bf16

    const float scaling = 0.17677669529663687f;

    convert_w<<<256, 256, 0, stream>>>(W, out_w, scaling, wbf, owbf);
    prep_kpos<<<dim3(PP, 2), 256, 0, stream>>>(pos_y, pos_x, W, kpb);

    int tiles = M / 128;                          // 784
    proj_mfma<<<dim3(tiles, 3), 512, 0, stream>>>(query, key, value, wbf, bias, scaling,
                                                  qb, kb, vb);

    attn_mfma<<<dim3(B, NHEAD), 256, 0, stream>>>(qb, kb, vb, kpb, maskp, qb, B);

    out_mfma<<<tiles, 512, 0, stream>>>(qb, owbf, out_b, out);
}

// Round 15
// 270.863 us; speedup vs baseline: 1.0572x; 1.0572x over previous
//
#include <hip/hip_runtime.h>
#include <hip/hip_bf16.h>

#define L_Q 49
#define D_MODEL 256
#define NHEAD 8
#define DK 32
#define PP 41
#define POS_OFF 20

typedef __attribute__((ext_vector_type(8))) __bf16 bf16x8;
typedef __attribute__((ext_vector_type(4))) float f32x4;
typedef __attribute__((ext_vector_type(8))) unsigned short u16x8;

__device__ __forceinline__ float bf2f(unsigned short u) {
    return __uint_as_float(((unsigned)u) << 16);
}
__device__ __forceinline__ unsigned short f2bf(float f) {
    unsigned u = __float_as_uint(f);
    return (unsigned short)((u + 0x7FFF + ((u >> 16) & 1)) >> 16);
}

// ---------------- fused one-time prep: W/out_w -> bf16 row-major (q-rows
// pre-scaled) for bx<256; kpos tables for bx>=256 (82 blocks).
__global__ __launch_bounds__(256)
void prep_all(const float* __restrict__ W, const float* __restrict__ out_w,
              const float* __restrict__ pos_y, const float* __restrict__ pos_x,
              float scaling,
              unsigned short* __restrict__ wbf, unsigned short* __restrict__ owbf,
              unsigned short* __restrict__ kpb) {
    int bx = blockIdx.x;
    if (bx < 256) {
        int i = bx * 256 + threadIdx.x;   // 65536 float4 total
        if (i < 49152) {
            int row = i >> 6;
            float sc = (row < 256) ? scaling : 1.0f;
            float4 v = reinterpret_cast<const float4*>(W)[i];
            ushort4 o = { f2bf(v.x * sc), f2bf(v.y * sc), f2bf(v.z * sc), f2bf(v.w * sc) };
            reinterpret_cast<ushort4*>(wbf)[i] = o;
        } else {
            float4 v = reinterpret_cast<const float4*>(out_w)[i - 49152];
            ushort4 o = { f2bf(v.x), f2bf(v.y), f2bf(v.z), f2bf(v.w) };
            reinterpret_cast<ushort4*>(owbf)[i - 49152] = o;
        }
    } else {
        int q = bx - 256;                 // 0..81
        int which = q / PP, p = q % PP;
        __shared__ float pr[128];
        int d = threadIdx.x;
        if (d < 128) pr[d] = which ? pos_x[p * 128 + d] : pos_y[p * 128 + d];
        __syncthreads();
        const float* Wk = W + 256 * 256;
        int fOff = which ? 128 : 0;
        float acc = 0.f;
        #pragma unroll 8
        for (int f = 0; f < 128; ++f)
            acc += pr[f] * Wk[(size_t)d * 256 + fOff + f];
        kpb[((size_t)which * PP + p) * 256 + d] = f2bf(acc);
    }
}

// ---------------- m97-style proj (r13 verbatim: best measured, 157 us)
__global__ __launch_bounds__(512)
void proj_mfma(const float* __restrict__ Xq, const float* __restrict__ Xk,
               const float* __restrict__ Xv,
               const unsigned short* __restrict__ Wb,   // row-major 768x256 bf16
               const float* __restrict__ bias, float scaling,
               unsigned short* __restrict__ outq, unsigned short* __restrict__ outk,
               unsigned short* __restrict__ outv) {
    __shared__ unsigned char Sz[65536];     // [0,32K): A dbuf; [32K,64K): B dbuf
    __shared__ float Lb[256];
    int which = blockIdx.y;
    const float* X = (which == 0) ? Xq : ((which == 1) ? Xk : Xv);
    unsigned short* out = (which == 0) ? outq : ((which == 1) ? outk : outv);
    const char* wsrc = (const char*)(Wb + (size_t)which * 65536);

    int tid = threadIdx.x, wid = tid >> 6, lane = tid & 63;
    int rgrp = lane & 15, kgrp = lane >> 4;
    int wm = wid & 1, wn = wid >> 1;
    size_t tile0 = (size_t)blockIdx.x * 128;
    const char* xsrc = (const char*)X;

    auto stage = [&](int kk, int buf) {
        #pragma unroll
        for (int it = 0; it < 2; ++it) {
            int c = wid + it * 8;
            {
                int arow = c * 8 + (lane >> 3);
                unsigned off = (unsigned)(lane & 7) * 16;
                unsigned gs = (unsigned)(kk * 128) + (off ^ (((unsigned)arow & 7) << 4));
                __builtin_amdgcn_global_load_lds(
                    xsrc + (tile0 + arow) * 1024 + gs,
                    (char*)Sz + buf * 16384 + c * 1024 + lane * 16, 16, 0, 0);
            }
            {
                int ncol = c * 16 + (lane >> 2);
                unsigned off = (unsigned)(lane & 3) * 16;
                unsigned gs = (unsigned)ncol * 512 + (unsigned)(kk * 64)
                            + (off ^ (((unsigned)ncol & 3) << 4));
                __builtin_amdgcn_global_load_lds(
                    wsrc + gs,
                    (char*)Sz + 32768 + buf * 16384 + c * 1024 + lane * 16, 16, 0, 0);
            }
        }
    };

    stage(0, 0);
    if (tid < 256) Lb[tid] = bias[which * 256 + tid] * ((which == 0) ? scaling : 1.0f);
    __syncthreads();

    f32x4 acc[4][4];
    #pragma unroll
    for (int m = 0; m < 4; ++m)
        #pragma unroll
        for (int n = 0; n < 4; ++n) acc[m][n] = (f32x4){0.f, 0.f, 0.f, 0.f};

    int buf = 0;
    for (int kk = 0; kk < 8; ++kk) {
        if (kk < 7) stage(kk + 1, buf ^ 1);

        const char* Az = (const char*)Sz + buf * 16384;
        const char* Bz = (const char*)Sz + 32768 + buf * 16384;

        bf16x8 bf[4];
        #pragma unroll
        for (int nt = 0; nt < 4; ++nt) {
            int ncol = wn * 64 + nt * 16 + rgrp;
            unsigned ad = (unsigned)ncol * 64
                        + (((unsigned)kgrp * 16) ^ (((unsigned)ncol & 3) << 4));
            bf[nt] = *reinterpret_cast<const bf16x8*>(Bz + ad);
        }
        #pragma unroll
        for (int mf = 0; mf < 4; ++mf) {
            int arow = wm * 64 + mf * 16 + rgrp;
            unsigned s = ((unsigned)arow & 7) << 4;
            unsigned a1 = (unsigned)arow * 128 + (((unsigned)kgrp * 32) ^ s);
            unsigned a2 = (unsigned)arow * 128 + (((unsigned)kgrp * 32 + 16) ^ s);
            f32x4 q0 = *reinterpret_cast<const f32x4*>(Az + a1);
            f32x4 q1 = *reinterpret_cast<const f32x4*>(Az + a2);
            bf16x8 af;
            af[0] = (__bf16)q0[0]; af[1] = (__bf16)q0[1];
            af[2] = (__bf16)q0[2]; af[3] = (__bf16)q0[3];
            af[4] = (__bf16)q1[0]; af[5] = (__bf16)q1[1];
            af[6] = (__bf16)q1[2]; af[7] = (__bf16)q1[3];
            #pragma unroll
            for (int nt = 0; nt < 4; ++nt)
                acc[mf][nt] = __builtin_amdgcn_mfma_f32_16x16x32_bf16(bf[nt], af, acc[mf][nt], 0, 0, 0);
        }
        __syncthreads();
        buf ^= 1;
    }

    #pragma unroll
    for (int mf = 0; mf < 4; ++mf) {
        size_t xrow = tile0 + wm * 64 + mf * 16 + rgrp;
        #pragma unroll
        for (int nt = 0; nt < 4; ++nt) {
            int col = wn * 64 + nt * 16 + kgrp * 4;
            float4 bv = *reinterpret_cast<const float4*>(&Lb[col]);
            ushort4 pk;
            pk.x = f2bf(acc[mf][nt][0] + bv.x);
            pk.y = f2bf(acc[mf][nt][1] + bv.y);
            pk.z = f2bf(acc[mf][nt][2] + bv.z);
            pk.w = f2bf(acc[mf][nt][3] + bv.w);
            *reinterpret_cast<ushort4*>(&out[xrow * 256 + col]) = pk;
        }
    }
}

// ---------------- out projection (r13 verbatim)
__global__ __launch_bounds__(512)
void out_mfma(const unsigned short* __restrict__ Xb, const unsigned short* __restrict__ Wb,
              const float* __restrict__ bias, float* __restrict__ out) {
    __shared__ unsigned char Sz[49152];
    __shared__ float Lb[256];
    int tid = threadIdx.x, wid = tid >> 6, lane = tid & 63;
    int rgrp = lane & 15, kgrp = lane >> 4;
    int wm = wid & 1, wn = wid >> 1;
    size_t tile0 = (size_t)blockIdx.x * 128;
    const char* xsrc = (const char*)Xb;
    const char* wsrc = (const char*)Wb;

    auto stage = [&](int kk, int buf) {
        {
            int arow = wid * 16 + (lane >> 2);
            unsigned off = (unsigned)(lane & 3) * 16;
            unsigned gs = (unsigned)(kk * 64) + (off ^ (((unsigned)arow & 3) << 4));
            __builtin_amdgcn_global_load_lds(
                xsrc + (tile0 + arow) * 512 + gs,
                (char*)Sz + buf * 8192 + wid * 1024 + lane * 16, 16, 0, 0);
        }
        #pragma unroll
        for (int it = 0; it < 2; ++it) {
            int c = wid + it * 8;
            int ncol = c * 16 + (lane >> 2);
            unsigned off = (unsigned)(lane & 3) * 16;
            unsigned gs = (unsigned)ncol * 512 + (unsigned)(kk * 64)
                        + (off ^ (((unsigned)ncol & 3) << 4));
            __builtin_amdgcn_global_load_lds(
                wsrc + gs,
                (char*)Sz + 16384 + buf * 16384 + c * 1024 + lane * 16, 16, 0, 0);
        }
    };

    stage(0, 0);
    if (tid < 256) Lb[tid] = bias[tid];
    __syncthreads();

    f32x4 acc[4][4];
    #pragma unroll
    for (int m = 0; m < 4; ++m)
        #pragma unroll
        for (int n = 0; n < 4; ++n) acc[m][n] = (f32x4){0.f, 0.f, 0.f, 0.f};

    int buf = 0;
    for (int kk = 0; kk < 8; ++kk) {
        if (kk < 7) stage(kk + 1, buf ^ 1);

        const char* Az = (const char*)Sz + buf * 8192;
        const char* Bz = (const char*)Sz + 16384 + buf * 16384;

        bf16x8 bf[4];
        #pragma unroll
        for (int nt = 0; nt < 4; ++nt) {
            int ncol = wn * 64 + nt * 16 + rgrp;
            unsigned ad = (unsigned)ncol * 64
                        + (((unsigned)kgrp * 16) ^ (((unsigned)ncol & 3) << 4));
            bf[nt] = *reinterpret_cast<const bf16x8*>(Bz + ad);
        }
        #pragma unroll
        for (int mf = 0; mf < 4; ++mf) {
            int arow = wm * 64 + mf * 16 + rgrp;
            unsigned ad = (unsigned)arow * 64
                        + (((unsigned)kgrp * 16) ^ (((unsigned)arow & 3) << 4));
            bf16x8 af = *reinterpret_cast<const bf16x8*>(Az + ad);
            #pragma unroll
            for (int nt = 0; nt < 4; ++nt)
                acc[mf][nt] = __builtin_amdgcn_mfma_f32_16x16x32_bf16(bf[nt], af, acc[mf][nt], 0, 0, 0);
        }
        __syncthreads();
        buf ^= 1;
    }

    #pragma unroll
    for (int mf = 0; mf < 4; ++mf) {
        size_t xrow = tile0 + wm * 64 + mf * 16 + rgrp;
        #pragma unroll
        for (int nt = 0; nt < 4; ++nt) {
            int col = wn * 64 + nt * 16 + kgrp * 4;
            float4 bv = *reinterpret_cast<const float4*>(&Lb[col]);
            float4 o;
            o.x = acc[mf][nt][0] + bv.x;
            o.y = acc[mf][nt][1] + bv.y;
            o.z = acc[mf][nt][2] + bv.z;
            o.w = acc[mf][nt][3] + bv.w;
            *reinterpret_cast<float4*>(&out[xrow * 256 + col]) = o;
        }
    }
}

// ---------------- MFMA fused attention: one (b, head-PAIR) per 8-wave block.
// Heads hg*2+lh, lh = wid>>2; waves w4 = wid&3 run the proven 4-wave algorithm
// per head. Head pair = 128 B contiguous => full-cache-line Q/K/V/kpos reads
// (old per-head blocks fetched 64 B of each 128-B line twice); mask/cumsum
// amortized over 2 heads; block count halves.
__global__ __launch_bounds__(512)
void attn_mfma(const unsigned short* __restrict__ qbuf,
               const unsigned short* __restrict__ kbuf,
               const unsigned short* __restrict__ vbuf,
               const unsigned short* __restrict__ kpb,
               const unsigned char* __restrict__ mask,
               unsigned short* __restrict__ ctx,
               int B) {
    __shared__ unsigned short Kp[2][96][40];
    __shared__ unsigned short Pt[2][64][72];
    __shared__ unsigned short Vt[2][32][72];
    __shared__ unsigned short postab[2][49][40];
    __shared__ int yy[L_Q], xx[L_Q];
    __shared__ unsigned char mb[52];

    int b = blockIdx.x, hg = blockIdx.y;       // heads hg*2, hg*2+1
    int tid = threadIdx.x, wid = tid >> 6, lane = tid & 63;
    int w4 = wid & 3, lh = wid >> 2;
    int rgrp = lane & 15, kgrp = lane >> 4;
    size_t lstride = (size_t)B * D_MODEL;
    size_t base = (size_t)b * D_MODEL + (size_t)hg * 64;   // head-pair base

    // ---- phase 0: cooperative staging (both heads)
    if (tid < L_Q) mb[tid] = mask[(size_t)b * L_Q + tid];
    if (tid < 392) {                        // V: 49 rows x 8 chunks (2 heads)
        int l = tid >> 3, c = tid & 7;
        int vlh = c >> 2, cc = c & 3;
        u16x8 vv = *reinterpret_cast<const u16x8*>(
            vbuf + (size_t)l * lstride + base + vlh * 32 + cc * 8);
        #pragma unroll
        for (int j = 0; j < 8; ++j) Vt[vlh][cc * 8 + j][l] = vv[j];
    }
    for (int e = tid; e < 1024; e += 512) { // zero Vt cols 49..63, both heads
        int zlh = e >> 9, r = e & 511;
        int d = r >> 4, s2 = 48 + (r & 15);
        if (s2 > 48) Vt[zlh][d][s2] = 0;
    }
    {                                       // K rows 0..63: 64 x 8 = 512 thr
        int r = tid >> 3, c = tid & 7, klh = c >> 2, kc = c & 3;
        int kr = min(r, 48);
        const unsigned short* src = kbuf + (size_t)kr * lstride + base + klh * 32 + kc * 8;
        *reinterpret_cast<u16x8*>(&Kp[klh][r][kc * 8]) = *reinterpret_cast<const u16x8*>(src);
    }
    if (tid < 256) {                        // kp rows 64..95 (kpy, kpx)
        int r2 = tid >> 3, c = tid & 7, klh = c >> 2, kc = c & 3;
        const unsigned short* src;
        if (r2 < 16)
            src = kpb + (size_t)(r2 + 13) * 256 + hg * 64 + klh * 32 + kc * 8;
        else
            src = kpb + (size_t)(PP + r2 - 16 + 13) * 256 + hg * 64 + klh * 32 + kc * 8;
        *reinterpret_cast<u16x8*>(&Kp[klh][64 + r2][kc * 8]) = *reinterpret_cast<const u16x8*>(src);
    }
    __syncthreads();
    if (tid < L_Q) {
        int r = tid / 7, c = tid % 7;
        int sy = 0, sx = 0;
        for (int rr = 0; rr <= r; ++rr) sy += (mb[rr * 7 + c] == 0);
        for (int cc = 0; cc <= c; ++cc) sx += (mb[r * 7 + cc] == 0);
        yy[tid] = sy; xx[tid] = sx;
    }
    __syncthreads();

    // ---- phase 1: S_full = Q . K'^T (6 MFMAs; wave w4 = row tile, head lh)
    int qrow = min(16 * w4 + rgrp, 48);
    bf16x8 qfrag = *reinterpret_cast<const bf16x8*>(
        qbuf + (size_t)qrow * lstride + base + lh * 32 + kgrp * 8);
    f32x4 acc[6];
    #pragma unroll
    for (int t = 0; t < 6; ++t) {
        bf16x8 bfrag = *reinterpret_cast<const bf16x8*>(&Kp[lh][t * 16 + rgrp][kgrp * 8]);
        acc[t] = __builtin_amdgcn_mfma_f32_16x16x32_bf16(qfrag, bfrag,
                    (f32x4){0.f, 0.f, 0.f, 0.f}, 0, 0, 0);
    }

    // ---- phase 2: spill pos tiles (own rows), assemble, softmax, write P
    #pragma unroll
    for (int i = 0; i < 4; ++i) {
        int l = 16 * w4 + kgrp * 4 + i;
        if (l <= 48) {
            postab[lh][l][rgrp]      = f2bf(acc[4][i]);
            postab[lh][l][20 + rgrp] = f2bf(acc[5][i]);
        }
    }
    asm volatile("s_waitcnt lgkmcnt(0)" ::: "memory");

    #pragma unroll
    for (int i = 0; i < 4; ++i) {
        int l = 16 * w4 + kgrp * 4 + i;
        int lc = min(l, 48);
        int yyl = yy[lc], xxl = xx[lc];
        float v[4];
        #pragma unroll
        for (int ct = 0; ct < 4; ++ct) {
            int s = ct * 16 + rgrp;
            int sc = min(s, 48);
            int iy = yyl - yy[sc] + (POS_OFF - 13);
            int ix = xxl - xx[sc] + (POS_OFF - 13);
            float val = acc[ct][i] + bf2f(postab[lh][lc][iy]) + bf2f(postab[lh][lc][20 + ix]);
            v[ct] = (s >= L_Q || mb[sc]) ? -1e30f : val;
        }
        float m = fmaxf(fmaxf(v[0], v[1]), fmaxf(v[2], v[3]));
        m = fmaxf(m, __shfl_xor(m, 1));
        m = fmaxf(m, __shfl_xor(m, 2));
        m = fmaxf(m, __shfl_xor(m, 4));
        m = fmaxf(m, __shfl_xor(m, 8));
        float ssum = 0.f, ex[4];
        #pragma unroll
        for (int ct = 0; ct < 4; ++ct) { ex[ct] = __expf(v[ct] - m); ssum += ex[ct]; }
        ssum += __shfl_xor(ssum, 1);
        ssum += __shfl_xor(ssum, 2);
        ssum += __shfl_xor(ssum, 4);
        ssum += __shfl_xor(ssum, 8);
        float is = 1.f / ssum;
        #pragma unroll
        for (int ct = 0; ct < 4; ++ct)
            Pt[lh][l & 63][ct * 16 + rgrp] = f2bf(ex[ct] * is);
    }
    asm volatile("s_waitcnt lgkmcnt(0)" ::: "memory");

    // ---- phase 3: PV (4 MFMAs) + store
    f32x4 oacc[2];
    oacc[0] = (f32x4){0.f, 0.f, 0.f, 0.f};
    oacc[1] = (f32x4){0.f, 0.f, 0.f, 0.f};
    #pragma unroll
    for (int kc = 0; kc < 2; ++kc) {
        bf16x8 pa = *reinterpret_cast<const bf16x8*>(&Pt[lh][16 * w4 + rgrp][kc * 32 + kgrp * 8]);
        #pragma unroll
        for (int dt = 0; dt < 2; ++dt) {
            bf16x8 vb = *reinterpret_cast<const bf16x8*>(&Vt[lh][dt * 16 + rgrp][kc * 32 + kgrp * 8]);
            oacc[dt] = __builtin_amdgcn_mfma_f32_16x16x32_bf16(pa, vb, oacc[dt], 0, 0, 0);
        }
    }
    #pragma unroll
    for (int dt = 0; dt < 2; ++dt)
        #pragma unroll
        for (int i = 0; i < 4; ++i) {
            int l = 16 * w4 + kgrp * 4 + i;
            if (l <= 48)
                ctx[(size_t)l * lstride + base + lh * 32 + dt * 16 + rgrp] = f2bf(oacc[dt][i]);
        }
}

extern "C" void kernel_launch(void* const* d_in, const int* in_sizes, int n_in,
                              void* d_out, int out_size, void* d_ws, size_t ws_size,
                              hipStream_t stream) {
    const float* query = (const float*)d_in[0];
    const float* key   = (const float*)d_in[1];
    const float* value = (const float*)d_in[2];
    const unsigned char* maskp = (const unsigned char*)d_in[3];
    const float* W     = (const float*)d_in[4];
    const float* bias  = (const float*)d_in[5];
    const float* out_w = (const float*)d_in[6];
    const float* out_b = (const float*)d_in[7];
    const float* pos_x = (const float*)d_in[8];
    const float* pos_y = (const float*)d_in[9];
    float* out = (float*)d_out;

    int B = in_sizes[0] / (L_Q * D_MODEL);        // 2048
    int M = L_Q * B;                              // 100352 = 784 * 128

    size_t nqkv = (size_t)M * D_MODEL;
    unsigned short* qb = (unsigned short*)d_ws;
    unsigned short* kb = qb + nqkv;
    unsigned short* vb = kb + nqkv;
    unsigned short* kpb = vb + nqkv;
    unsigned short* wbf = kpb + 2 * PP * D_MODEL; // row-major 768x256 bf16
    unsigned short* owbf = wbf + 768 * 256;       // row-major 256x256 bf16

    const float scaling = 0.17677669529663687f;

    prep_all<<<256 + 2 * PP, 256, 0, stream>>>(W, out_w, pos_y, pos_x, scaling,
                                               wbf, owbf, kpb);

    int tiles = M / 128;                          // 784
    proj_mfma<<<dim3(tiles, 3), 512, 0, stream>>>(query, key, value, wbf, bias, scaling,
                                                  qb, kb, vb);

    attn_mfma<<<dim3(B, NHEAD / 2), 512, 0, stream>>>(qb, kb, vb, kpb, maskp, qb, B);

    out_mfma<<<tiles, 512, 0, stream>>>(qb, owbf, out_b, out);
}